// Round 2
// baseline (373.686 us; speedup 1.0000x reference)
//
#include <hip/hip_runtime.h>

// ModulatedConv2d (StyleGAN2): B=8, CIN=COUT=64, K=3, H=W=256, SDIM=512
// Strategy: bf16 MFMA implicit GEMM (9 shifted GEMMs, one per tap).
//   ws layout:
//     X  : bf16 [B][256][256][64]  (input transposed, cin innermost)  @ 0,        67108864 B
//     wA : bf16 [B][64][9][64]     (demodulated weights, cin innermost) @ 67108864, 589824 B
//     s  : f32  [B][64]            (style modulation)                  @ 67698688, 2048 B

#define CIN   64
#define COUT  64
#define SDIM  512
#define HW    256

typedef short bf16x8 __attribute__((ext_vector_type(8)));
typedef float f32x4  __attribute__((ext_vector_type(4)));
typedef unsigned short u16;

static __device__ __forceinline__ u16 f2bf(float f) {
    union { float f; unsigned u; } v; v.f = f;
    unsigned r = v.u + 0x7FFF + ((v.u >> 16) & 1);   // RTN-even
    return (u16)(r >> 16);
}

// ---------------- kernel 1: style modulation s[b][cin] ----------------
__global__ void k_style(const float* __restrict__ style, const float* __restrict__ mw,
                        const float* __restrict__ mb, float* __restrict__ s_out) {
    int b = blockIdx.x;            // 8 blocks x 256 threads
    int t = threadIdx.x;
    int cin = t & 63, seg = t >> 6;   // 4 segments of 128 elems
    const float4* st = (const float4*)(style + (size_t)b * SDIM) + seg * 32;
    const float4* w  = (const float4*)(mw + (size_t)cin * SDIM) + seg * 32;
    float acc = 0.f;
#pragma unroll 8
    for (int i = 0; i < 32; i++) {
        float4 a = st[i], bb = w[i];
        acc += a.x * bb.x + a.y * bb.y + a.z * bb.z + a.w * bb.w;
    }
    __shared__ float red[4][64];
    red[seg][cin] = acc;
    __syncthreads();
    if (seg == 0) {
        float v = red[0][cin] + red[1][cin] + red[2][cin] + red[3][cin];
        s_out[b * CIN + cin] = v * 0.04419417382415922f + mb[cin];  // 1/sqrt(512)
    }
}

// ------------- kernel 2: modulate + demodulate -> bf16 wA[b][cout][kk][cin] -------------
__global__ void k_wdemod(const float* __restrict__ weight, const float* __restrict__ s,
                         u16* __restrict__ wA) {
    int bid = blockIdx.x;             // B*COUT = 512 blocks x 64 threads
    int b = bid >> 6, co = bid & 63;
    int cin = threadIdx.x;
    float sv = s[b * CIN + cin] * (1.0f / 24.0f);   // scale = 1/sqrt(64*9)
    const float* wp = weight + ((size_t)co * CIN + cin) * 9;
    float w[9]; float sq = 0.f;
#pragma unroll
    for (int k = 0; k < 9; k++) { w[k] = wp[k] * sv; sq += w[k] * w[k]; }
#pragma unroll
    for (int off = 32; off; off >>= 1) sq += __shfl_xor(sq, off, 64);
    float dm = 1.0f / sqrtf(sq + 1e-8f);
    u16* dst = wA + (((size_t)b * COUT + co) * 9) * 64 + cin;
#pragma unroll
    for (int k = 0; k < 9; k++) dst[k * 64] = f2bf(w[k] * dm);
}

// ------------- kernel 3: NCHW fp32 -> X[b][y][x][cin] bf16 (LDS tile transpose) -------------
__global__ void k_transpose(const float* __restrict__ in, u16* __restrict__ X) {
    // grid: B * H * (W/64) = 8192 blocks x 256 threads; tile = 64 cin x 64 w at fixed (b,h)
    int bid = blockIdx.x;
    int wblk = bid & 3, h = (bid >> 2) & 255, b = bid >> 10;
    int w0 = wblk * 64;
    __shared__ u16 lds[64][65];     // [cin][dw], +1 pad
    int t = threadIdx.x;
    const float* src = in + (size_t)b * CIN * 65536 + (size_t)h * 256 + w0;
    int dw = t & 63, c0 = t >> 6;
#pragma unroll
    for (int i = 0; i < 16; i++) {
        int cin = i * 4 + c0;
        lds[cin][dw] = f2bf(src[(size_t)cin * 65536 + dw]);
    }
    __syncthreads();
    u16* dst = X + (((size_t)b * 256 + h) * 256 + w0) * 64;
#pragma unroll
    for (int i = 0; i < 4; i++) {
        int u = i * 256 + t;
        int dw2 = u >> 4, c4 = (u & 15) * 4;
        ushort4 val;
        val.x = lds[c4 + 0][dw2]; val.y = lds[c4 + 1][dw2];
        val.z = lds[c4 + 2][dw2]; val.w = lds[c4 + 3][dw2];
        *(ushort4*)(dst + (size_t)dw2 * 64 + c4) = val;
    }
}

// ------------- kernel 4: implicit-GEMM conv, bf16 MFMA 16x16x32 -------------
// block = 256 thr (4 waves). Tile: all 64 cout x (64x * 4y) pixels; wave w owns row y0+w.
// Per wave: 4 cout-tiles x 4 x-tiles; per K-chunk (tap kk, cin-half): 8 frag loads + 16 MFMA.
__global__ __launch_bounds__(256, 2) void k_conv(
        const u16* __restrict__ X, const u16* __restrict__ wA,
        float* __restrict__ out) {
    int bid = blockIdx.x;
    int b = bid >> 8, r = bid & 255;
    int y0 = (r >> 2) << 2;
    int x0 = (r & 3) << 6;
    int wv = threadIdx.x >> 6;
    int l  = threadIdx.x & 63;
    int lr = l & 15, lg = l >> 4;
    int y = y0 + wv;

    f32x4 acc[4][4];
#pragma unroll
    for (int ct = 0; ct < 4; ct++)
#pragma unroll
        for (int xt = 0; xt < 4; xt++) acc[ct][xt] = (f32x4){0.f, 0.f, 0.f, 0.f};

    const u16* Xb  = X  + (size_t)b * 65536 * 64;
    const u16* wAb = wA + (size_t)b * COUT * 9 * 64;

#pragma unroll
    for (int kk = 0; kk < 9; kk++) {
        const int dh = kk / 3, dw = kk % 3;
        int yy = y + dh - 1;
        if (yy < 0 || yy > 255) continue;           // wave-uniform
        const u16* Xrow = Xb + (size_t)yy * 256 * 64;
#pragma unroll
        for (int half = 0; half < 2; half++) {
            bf16x8 afr[4], bfr[4];
#pragma unroll
            for (int ct = 0; ct < 4; ct++) {
                // A[row=cout=ct*16+lr][k: cin = half*32 + lg*8 + j]
                afr[ct] = *(const bf16x8*)(wAb + (((size_t)(ct * 16 + lr)) * 9 + kk) * 64
                                           + half * 32 + lg * 8);
            }
#pragma unroll
            for (int xt = 0; xt < 4; xt++) {
                int xx = x0 + xt * 16 + lr + dw - 1;
                bf16x8 v = {0, 0, 0, 0, 0, 0, 0, 0};
                if (xx >= 0 && xx < 256)
                    v = *(const bf16x8*)(Xrow + (size_t)xx * 64 + half * 32 + lg * 8);
                bfr[xt] = v;
            }
#pragma unroll
            for (int ct = 0; ct < 4; ct++)
#pragma unroll
                for (int xt = 0; xt < 4; xt++)
                    acc[ct][xt] = __builtin_amdgcn_mfma_f32_16x16x32_bf16(
                        afr[ct], bfr[xt], acc[ct][xt], 0, 0, 0);
        }
    }

    // epilogue: D col = lane&15 -> pixel, row = (lane>>4)*4 + q -> cout
    float* ob = out + (size_t)b * COUT * 65536 + (size_t)y * 256 + x0;
#pragma unroll
    for (int ct = 0; ct < 4; ct++)
#pragma unroll
        for (int xt = 0; xt < 4; xt++)
#pragma unroll
            for (int q = 0; q < 4; q++) {
                int cout = ct * 16 + lg * 4 + q;
                ob[(size_t)cout * 65536 + xt * 16 + lr] = acc[ct][xt][q];
            }
}

extern "C" void kernel_launch(void* const* d_in, const int* in_sizes, int n_in,
                              void* d_out, int out_size, void* d_ws, size_t ws_size,
                              hipStream_t stream) {
    const float* input      = (const float*)d_in[0];
    const float* style      = (const float*)d_in[1];
    const float* weight     = (const float*)d_in[2];
    const float* mod_weight = (const float*)d_in[3];
    const float* mod_bias   = (const float*)d_in[4];
    float* out = (float*)d_out;

    char* ws = (char*)d_ws;
    u16*   X  = (u16*)ws;                                   // 67108864 B
    u16*   wA = (u16*)(ws + 67108864);                      // 589824 B
    float* s  = (float*)(ws + 67108864 + 589824);           // 2048 B

    k_style    <<<8,    256, 0, stream>>>(style, mod_weight, mod_bias, s);
    k_wdemod   <<<512,  64,  0, stream>>>(weight, s, wA);
    k_transpose<<<8192, 256, 0, stream>>>(input, X);
    k_conv     <<<2048, 256, 0, stream>>>(X, wA, out);
}

// Round 4
// 324.390 us; speedup vs baseline: 1.1520x; 1.1520x over previous
//
#include <hip/hip_runtime.h>
#include <hip/hip_bf16.h>

// ModulatedConv2d fused: B=8, CIN=COUT=64, K=3, H=W=256, SDIM=512
// Round 3: single fused conv kernel (transpose folded in).
//  - stage input tile fp32->bf16 into LDS [6][72][64] (cin innermost),
//    XOR-swizzle byte^=((xl&7)<<4) -> conflict-free ds_read_b128 B-fragments
//  - 288x mfma_f32_16x16x32_bf16 per wave (4ct x 4xt x 9taps x 2halves)
//  - epilogue: LDS-bounce transpose so global stores are float4 (full 64B lines)
//  ws: wA bf16 [B][64cout][9][64cin] @0 (589824 B), s f32 [B][64] @589824

#define CIN   64
#define COUT  64
#define SDIM  512

typedef short bf16x8 __attribute__((ext_vector_type(8)));
typedef float f32x4  __attribute__((ext_vector_type(4)));
typedef unsigned short u16;
typedef unsigned short us8 __attribute__((ext_vector_type(8)));

static __device__ __forceinline__ u16 f2bf(float f) {
    union { float f; unsigned u; } v; v.f = f;
    unsigned r = v.u + 0x7FFF + ((v.u >> 16) & 1);   // RTN-even
    return (u16)(r >> 16);
}
static __device__ __forceinline__ float getc(const float4& f, int k) {
    return k == 0 ? f.x : k == 1 ? f.y : k == 2 ? f.z : f.w;
}

// ---------------- kernel 1: style modulation s[b][cin] ----------------
__global__ void k_style(const float* __restrict__ style, const float* __restrict__ mw,
                        const float* __restrict__ mb, float* __restrict__ s_out) {
    int b = blockIdx.x;            // 8 blocks x 256 threads
    int t = threadIdx.x;
    int cin = t & 63, seg = t >> 6;
    const float4* st = (const float4*)(style + (size_t)b * SDIM) + seg * 32;
    const float4* w  = (const float4*)(mw + (size_t)cin * SDIM) + seg * 32;
    float acc = 0.f;
#pragma unroll 8
    for (int i = 0; i < 32; i++) {
        float4 a = st[i], bb = w[i];
        acc += a.x * bb.x + a.y * bb.y + a.z * bb.z + a.w * bb.w;
    }
    __shared__ float red[4][64];
    red[seg][cin] = acc;
    __syncthreads();
    if (seg == 0) {
        float v = red[0][cin] + red[1][cin] + red[2][cin] + red[3][cin];
        s_out[b * CIN + cin] = v * 0.04419417382415922f + mb[cin];  // 1/sqrt(512)
    }
}

// ------------- kernel 2: modulate + demodulate -> bf16 wA[b][cout][kk][cin] -------------
__global__ void k_wdemod(const float* __restrict__ weight, const float* __restrict__ s,
                         u16* __restrict__ wA) {
    int bid = blockIdx.x;             // B*COUT = 512 blocks x 64 threads
    int b = bid >> 6, co = bid & 63;
    int cin = threadIdx.x;
    float sv = s[b * CIN + cin] * (1.0f / 24.0f);   // scale = 1/sqrt(64*9)
    const float* wp = weight + ((size_t)co * CIN + cin) * 9;
    float w[9]; float sq = 0.f;
#pragma unroll
    for (int k = 0; k < 9; k++) { w[k] = wp[k] * sv; sq += w[k] * w[k]; }
#pragma unroll
    for (int off = 32; off; off >>= 1) sq += __shfl_xor(sq, off, 64);
    float dm = 1.0f / sqrtf(sq + 1e-8f);
    u16* dst = wA + (((size_t)b * COUT + co) * 9) * 64 + cin;
#pragma unroll
    for (int k = 0; k < 9; k++) dst[k * 64] = f2bf(w[k] * dm);
}

// ------------- kernel 3: fused stage+conv+epilogue -------------
// block = 256 thr (4 waves); tile = one batch b, 4 y rows x 64 x, all 64 cout.
// LDS: bf16 X [yl=6][xl=72][cin=64], byte^=((xl&7)<<4) swizzle. 55296 B -> 2 blk/CU.
__global__ __launch_bounds__(256, 2) void k_conv2(
        const float* __restrict__ in, const u16* __restrict__ wA,
        float* __restrict__ out) {
    __shared__ __align__(16) u16 Xs[6 * 72 * 64];   // 55296 B

    int raw = blockIdx.x;
    int swz = (raw & 7) * 256 + (raw >> 3);         // XCD swizzle: batch per XCD
    int b = swz >> 8, r = swz & 255;
    int y0 = (r >> 2) * 4, x0 = (r & 3) * 64;
    int tid = threadIdx.x;

    // ---- stage: 864 units = 6y x 18(x4) x 8(cin-group); unit loads 8x float4,
    //      register-transposes to 4x ds_write_b128 ([x][cin8] 16B each) ----
    const float* inb = in + (size_t)b * (CIN * 65536);
    for (int u = tid; u < 864; u += 256) {
        int cing = u & 7;
        int g = u >> 3;
        int x4 = g % 18, yy = g / 18;
        int y = y0 + yy - 1;
        int x = x0 - 4 + x4 * 4;                    // float4-aligned; fully in or out
        float4 f[8];
        if (y >= 0 && y < 256 && x >= 0 && x < 253) {
            const float* p = inb + (size_t)(cing * 8) * 65536 + (size_t)y * 256 + x;
#pragma unroll
            for (int j = 0; j < 8; j++) f[j] = *(const float4*)(p + (size_t)j * 65536);
        } else {
#pragma unroll
            for (int j = 0; j < 8; j++) f[j] = make_float4(0.f, 0.f, 0.f, 0.f);
        }
#pragma unroll
        for (int k = 0; k < 4; k++) {
            union { us8 v; unsigned w[4]; } pk;
#pragma unroll
            for (int p2 = 0; p2 < 4; p2++) {
                __hip_bfloat162 h = __float22bfloat162_rn(
                    make_float2(getc(f[2 * p2], k), getc(f[2 * p2 + 1], k)));
                unsigned wv_; __builtin_memcpy(&wv_, &h, 4);
                pk.w[p2] = wv_;
            }
            int xl = x4 * 4 + k;
            unsigned bo = (unsigned)(((yy * 72 + xl) * 64 + cing * 8) * 2)
                        ^ ((unsigned)(xl & 7) << 4);
            *(us8*)((char*)Xs + bo) = pk.v;
        }
    }
    __syncthreads();

    // ---- compute ----
    int wv = tid >> 6, l = tid & 63, lr = l & 15, lg = l >> 4;
    const u16* wAb = wA + (size_t)b * (COUT * 9 * 64);

    f32x4 acc[4][4];
#pragma unroll
    for (int ct = 0; ct < 4; ct++)
#pragma unroll
        for (int xt = 0; xt < 4; xt++) acc[ct][xt] = (f32x4){0.f, 0.f, 0.f, 0.f};

#pragma unroll
    for (int kk = 0; kk < 9; kk++) {
        const int dh = kk / 3, dw = kk % 3;
        const int yl = wv + dh;
#pragma unroll
        for (int half = 0; half < 2; half++) {
            bf16x8 afr[4], bfr[4];
#pragma unroll
            for (int ct = 0; ct < 4; ct++)
                afr[ct] = *(const bf16x8*)(wAb + ((size_t)(ct * 16 + lr) * 9 + kk) * 64
                                           + half * 32 + lg * 8);
#pragma unroll
            for (int xt = 0; xt < 4; xt++) {
                int xl = xt * 16 + lr + dw + 3;
                unsigned bo = (unsigned)(((yl * 72 + xl) * 64 + half * 32 + lg * 8) * 2)
                            ^ ((unsigned)(xl & 7) << 4);
                bfr[xt] = *(const bf16x8*)((const char*)Xs + bo);
            }
#pragma unroll
            for (int ct = 0; ct < 4; ct++)
#pragma unroll
                for (int xt = 0; xt < 4; xt++)
                    acc[ct][xt] = __builtin_amdgcn_mfma_f32_16x16x32_bf16(
                        afr[ct], bfr[xt], acc[ct][xt], 0, 0, 0);
        }
    }

    // ---- epilogue: per-wave LDS bounce -> float4 stores (full 64B lines) ----
    __syncthreads();                                 // all waves done reading Xs
    float* ep = ((float*)Xs) + wv * (16 * 68);       // 4352 B per wave, stride-68 rows
    float* ob = out + ((size_t)b * COUT) * 65536 + (size_t)(y0 + wv) * 256 + x0;
    int c = l >> 2, xq = l & 3;
#pragma unroll
    for (int ct = 0; ct < 4; ct++) {
#pragma unroll
        for (int xt = 0; xt < 4; xt++)
#pragma unroll
            for (int q = 0; q < 4; q++)
                ep[(lg * 4 + q) * 68 + xt * 16 + lr] = acc[ct][xt][q];
        asm volatile("s_waitcnt lgkmcnt(0)" ::: "memory");
#pragma unroll
        for (int k = 0; k < 4; k++) {
            float4 v = *(const float4*)(ep + c * 68 + k * 16 + xq * 4);
            *(float4*)(ob + (size_t)(ct * 16 + c) * 65536 + k * 16 + xq * 4) = v;
        }
    }
}

extern "C" void kernel_launch(void* const* d_in, const int* in_sizes, int n_in,
                              void* d_out, int out_size, void* d_ws, size_t ws_size,
                              hipStream_t stream) {
    const float* input      = (const float*)d_in[0];
    const float* style      = (const float*)d_in[1];
    const float* weight     = (const float*)d_in[2];
    const float* mod_weight = (const float*)d_in[3];
    const float* mod_bias   = (const float*)d_in[4];
    float* out = (float*)d_out;

    char* ws = (char*)d_ws;
    u16*   wA = (u16*)ws;                       // 589824 B
    float* s  = (float*)(ws + 589824);          // 2048 B

    k_style <<<8,    256, 0, stream>>>(style, mod_weight, mod_bias, s);
    k_wdemod<<<512,  64,  0, stream>>>(weight, s, wA);
    k_conv2 <<<2048, 256, 0, stream>>>(input, wA, out);
}